// Round 1
// baseline (1094.542 us; speedup 1.0000x reference)
//
#include <hip/hip_runtime.h>
#include <hip/hip_bf16.h>

// ---------------- problem dims ----------------
constexpr int B_=4, C_=64, T_=8, X_=96, Y_=96;
constexpr int XY_  = X_*Y_;            // 9216
constexpr int TOT_ = B_*C_*T_*XY_;     // 18874368
constexpr float EPS_   = 1e-5f;
constexpr float SLOPE_ = 0.01f;
constexpr float QSC_   = 0.35355339059327373f;   // 1/sqrt(8)
constexpr float INV_BN_ = 1.0f/294912.0f;        // 1/(B*T*X*Y)
constexpr float INV_XY_ = 1.0f/9216.0f;

// ---------------- ws layout (bytes) ----------------
constexpr size_t OFF_X0   = 0;                        // f32 [B][C][T][X][Y]
constexpr size_t OFF_X2   = (size_t)TOT_*4;           // bf16 [n][t][c]  (n = b*9216 + x*96 + y)
constexpr size_t OFF_WT   = OFF_X2 + (size_t)TOT_*2;  // f32 [ci][k][co] 36864
constexpr size_t OFF_SUM0 = OFF_WT + 147456;
constexpr size_t OFF_SQ0  = OFF_SUM0 + 256;
constexpr size_t OFF_SUM1 = OFF_SQ0 + 256;
constexpr size_t OFF_SQ1  = OFF_SUM1 + 256;
constexpr size_t OFF_M    = OFF_SQ1 + 256;            // 2048 f32 [b][t][c]
constexpr size_t ZBYTES   = 1024 + 8192;              // zeroed region starts at OFF_SUM0
constexpr size_t OFF_SC0  = OFF_M + 8192;
constexpr size_t OFF_SH0  = OFF_SC0 + 256;
constexpr size_t OFF_SC1  = OFF_SH0 + 256;
constexpr size_t OFF_SH1  = OFF_SC1 + 256;
constexpr size_t OFF_KERN = OFF_SH1 + 256;            // 800 f32 [b][t][25]

__device__ __forceinline__ float leaky_(float v){ return v >= 0.f ? v : SLOPE_*v; }

// ---------------- K0: transpose conv0 weights -> wT[ci][k][co] ----------------
__global__ void k_prep(const float* __restrict__ w0, float* __restrict__ wT){
    int i = blockIdx.x*256 + threadIdx.x;             // 36864 total
    if (i >= 64*64*9) return;
    int co = i & 63; int k = (i >> 6) % 9; int ci = i / 576;
    wT[i] = w0[co*576 + ci*9 + k];
}

// ---------------- K1: conv0 (1x3x3, pad 1) + bias -> x0 ; fused BN0 partial stats ------
// block: 256 thr = (co 0..63, g 0..3).  tile: (b,t) fixed, x rows xr0..xr0+3, y0..y0+15, all co.
__global__ __launch_bounds__(256) void k_conv0(const float* __restrict__ h,
        const float* __restrict__ wT, const float* __restrict__ bias,
        float* __restrict__ x0, float* __restrict__ sum0, float* __restrict__ sq0){
    __shared__ float s_in[64*6*20];                   // [ci][row 6][col 20] (18 valid)
    int bt = blockIdx.y; int b = bt >> 3, t = bt & 7;
    int tile = blockIdx.x; int xt = tile / 6, yt = tile % 6;
    int xr0 = xt*4, y0 = yt*16;
    const float* hb = h + ((size_t)(b*64)*8 + t)*9216;
    for (int s = threadIdx.x; s < 7680; s += 256){
        int col = s % 20; int r = (s/20) % 6; int ci = s / 120;
        int xx = xr0 + r - 1, yy = y0 + col - 1;
        float v = 0.f;
        if (col < 18 && xx >= 0 && xx < 96 && yy >= 0 && yy < 96)
            v = hb[(size_t)ci*73728 + xx*96 + yy];
        s_in[s] = v;
    }
    __syncthreads();
    int co = threadIdx.x & 63, g = threadIdx.x >> 6;
    float bv = bias[co];
    float acc[16];
    #pragma unroll
    for (int j=0;j<16;j++) acc[j] = bv;
    for (int ci=0; ci<64; ci++){
        float w[9];
        #pragma unroll
        for (int k=0;k<9;k++) w[k] = wT[(ci*9+k)*64 + co];
        #pragma unroll
        for (int dx=0; dx<3; dx++){
            const float* row = &s_in[ci*120 + (g+dx)*20];
            float r[18];
            #pragma unroll
            for (int m=0;m<18;m++) r[m] = row[m];
            #pragma unroll
            for (int dy=0;dy<3;dy++){
                float wv = w[dx*3+dy];
                #pragma unroll
                for (int j=0;j<16;j++) acc[j] += wv * r[j+dy];
            }
        }
    }
    float* op = x0 + ((size_t)(b*64+co)*8 + t)*9216 + (xr0+g)*96 + y0;
    #pragma unroll
    for (int j4=0;j4<4;j4++)
        *(float4*)(op + j4*4) = make_float4(acc[j4*4],acc[j4*4+1],acc[j4*4+2],acc[j4*4+3]);
    // fused BN0 partial stats
    float ls=0.f, lq=0.f;
    #pragma unroll
    for (int j=0;j<16;j++){ ls += acc[j]; lq += acc[j]*acc[j]; }
    __syncthreads();
    float* red = s_in;
    red[g*64+co] = ls; red[256 + g*64+co] = lq;
    __syncthreads();
    if (threadIdx.x < 64){
        int c = threadIdx.x;
        float a = red[c] + red[64+c] + red[128+c] + red[192+c];
        float q = red[256+c] + red[320+c] + red[384+c] + red[448+c];
        atomicAdd(&sum0[c], a);
        atomicAdd(&sq0[c], q);
    }
}

// ---------------- finalize BN scale/shift ----------------
__global__ void k_fin(const float* __restrict__ sum, const float* __restrict__ sq,
                      const float* __restrict__ g, const float* __restrict__ be,
                      float* __restrict__ scale, float* __restrict__ shift, float inv_n){
    int c = threadIdx.x;
    float mu = sum[c]*inv_n;
    float var = sq[c]*inv_n - mu*mu;
    float rs = rsqrtf(var + EPS_);
    float sc = g[c]*rs;
    scale[c] = sc; shift[c] = be[c] - mu*sc;
}

// ---------------- A12: fused BN0-apply + leaky + MHA (T=8) + out_proj + residual -> x2 bf16
// block 256 thr; 16 positions (fixed b,x, y0..y0+15); tok = p*8 + t (128 tokens)
__global__ __launch_bounds__(256) void k_attn(const float* __restrict__ x0,
        const float* __restrict__ sc0, const float* __restrict__ sh0,
        const float* __restrict__ wqkv, const float* __restrict__ bqkv,
        const float* __restrict__ wo,   const float* __restrict__ bo,
        __hip_bfloat16* __restrict__ x2){
    __shared__ __hip_bfloat16 x1s[64][136];   // [c][tok]
    __shared__ float qs[24][132];             // per-head q(0-7) k(8-15) v(16-23)
    __shared__ __hip_bfloat16 om[64][136];    // o_mid [c][tok]
    int yt = blockIdx.x, xx = blockIdx.y, b = blockIdx.z;
    int y0 = yt*16;
    int tid = threadIdx.x;
    // phase 0: load x0 slab, apply bn0+leaky, stage bf16
    for (int s = tid; s < 8192; s += 256){
        int j = s & 15; int t = (s >> 4) & 7; int c = s >> 7;
        int cu = __builtin_amdgcn_readfirstlane(c);   // wave-uniform
        float v = x0[((size_t)(b*64+c)*8 + t)*9216 + xx*96 + y0 + j];
        v = leaky_(v*sc0[cu] + sh0[cu]);
        x1s[c][j*8+t] = __float2bfloat16(v);
    }
    __syncthreads();
    int tok = tid & 127, grp = tid >> 7;              // grp wave-uniform
    for (int hh=0; hh<8; hh++){
        // ---- phase 1: qkv for head hh (128 tok x 24) ----
        float acc[12];
        int rows[12];
        #pragma unroll
        for (int i=0;i<12;i++){
            int e = grp*12 + i;
            int r = (e<8) ? hh*8+e : (e<16) ? 64 + hh*8 + (e-8) : 128 + hh*8 + (e-16);
            rows[i] = __builtin_amdgcn_readfirstlane(r);
            acc[i] = bqkv[rows[i]];
        }
        #pragma unroll
        for (int cb=0; cb<64; cb+=16){
            float xv[16];
            #pragma unroll
            for (int cc=0;cc<16;cc++) xv[cc] = __bfloat162float(x1s[cb+cc][tok]);
            #pragma unroll
            for (int i=0;i<12;i++){
                const float* wr = wqkv + rows[i]*64 + cb;   // scalar loads
                #pragma unroll
                for (int cc=0;cc<16;cc++) acc[i] += xv[cc]*wr[cc];
            }
        }
        #pragma unroll
        for (int i=0;i<12;i++){
            int e = grp*12 + i;
            qs[e][tok] = (e<8) ? acc[i]*QSC_ : acc[i];
        }
        __syncthreads();
        // ---- phase 2: scores + softmax + PV (threads 0..127) ----
        if (tid < 128){
            int p = tid >> 3, qt = tid & 7;
            int tq = p*8 + qt;
            float qv[8];
            #pragma unroll
            for (int d=0;d<8;d++) qv[d] = qs[d][tq];
            float sv[8]; float mx = -1e30f;
            #pragma unroll
            for (int kt=0;kt<8;kt++){
                float s = 0.f;
                #pragma unroll
                for (int d=0;d<8;d++) s += qv[d]*qs[8+d][p*8+kt];
                sv[kt] = s; mx = fmaxf(mx, s);
            }
            float ssum = 0.f;
            #pragma unroll
            for (int kt=0;kt<8;kt++){ sv[kt] = __expf(sv[kt]-mx); ssum += sv[kt]; }
            float inv = 1.f/ssum;
            #pragma unroll
            for (int d=0;d<8;d++){
                float o = 0.f;
                #pragma unroll
                for (int kt=0;kt<8;kt++) o += sv[kt]*qs[16+d][p*8+kt];
                om[hh*8+d][tq] = __float2bfloat16(o*inv);
            }
        }
        __syncthreads();
    }
    // ---- phase 3: out_proj + residual -> x2 ----
    {
        float acc[32];
        #pragma unroll
        for (int i=0;i<32;i++) acc[i] = bo[grp*32+i];
        #pragma unroll
        for (int cb=0; cb<64; cb+=16){
            float xv[16];
            #pragma unroll
            for (int cc=0;cc<16;cc++) xv[cc] = __bfloat162float(om[cb+cc][tok]);
            #pragma unroll
            for (int i=0;i<32;i++){
                int ru = __builtin_amdgcn_readfirstlane(grp*32+i);
                const float* wr = wo + ru*64 + cb;          // scalar loads
                #pragma unroll
                for (int cc=0;cc<16;cc++) acc[i] += xv[cc]*wr[cc];
            }
        }
        int p = tok >> 3, t = tok & 7;
        size_t n = (size_t)b*9216 + xx*96 + y0 + p;
        __hip_bfloat16* out = x2 + (n*8 + t)*64 + grp*32;
        #pragma unroll
        for (int i=0;i<32;i++){
            float v = acc[i] + __bfloat162float(x1s[grp*32+i][tok]);
            out[i] = __float2bfloat16(v);
        }
    }
}

// ---------------- stats over x2 (BN1) ----------------
__global__ __launch_bounds__(256) void k_stats1(const __hip_bfloat16* __restrict__ x2,
        float* __restrict__ sum1, float* __restrict__ sq1){
    __shared__ float red[512];
    int c = threadIdx.x & 63, w = threadIdx.x >> 6;
    size_t tk0 = (size_t)blockIdx.x * 512;
    float s = 0.f, q = 0.f;
    for (int tk = w; tk < 512; tk += 4){
        float v = __bfloat162float(x2[(tk0 + tk)*64 + c]);
        s += v; q += v*v;
    }
    red[w*64+c] = s; red[256 + w*64+c] = q;
    __syncthreads();
    if (threadIdx.x < 64){
        int cc = threadIdx.x;
        float a = red[cc] + red[64+cc] + red[128+cc] + red[192+cc];
        float qq = red[256+cc] + red[320+cc] + red[384+cc] + red[448+cc];
        atomicAdd(&sum1[cc], a);
        atomicAdd(&sq1[cc], qq);
    }
}

// ---------------- m partial sums: sum over (x,y) of leaky(bn1(x2)) ----------------
__global__ __launch_bounds__(256) void k_m(const __hip_bfloat16* __restrict__ x2,
        const float* __restrict__ sc1, const float* __restrict__ sh1,
        float* __restrict__ msum){
    int c = threadIdx.x & 63, tg = threadIdx.x >> 6;
    int b = blockIdx.y, chunk = blockIdx.x;
    float macc[8] = {0,0,0,0,0,0,0,0};
    float sc = sc1[c], sh = sh1[c];
    int xy_end = chunk*384 + 384;
    for (int xy = chunk*384 + tg; xy < xy_end; xy += 4){
        size_t base = ((size_t)(b*9216 + xy)*8)*64 + c;
        #pragma unroll
        for (int t=0;t<8;t++){
            float v = __bfloat162float(x2[base + (size_t)t*64]);
            macc[t] += leaky_(v*sc + sh);
        }
    }
    #pragma unroll
    for (int t=0;t<8;t++) atomicAdd(&msum[(b*8+t)*64 + c], macc[t]);
}

// ---------------- kern[b][t][25] = conv1(m) ----------------
__global__ void k_kern(const float* __restrict__ msum, const float* __restrict__ w1,
                       const float* __restrict__ b1, float* __restrict__ kern){
    int tid = blockIdx.x*256 + threadIdx.x;
    if (tid >= 800) return;
    int o = tid % 25; int t = (tid/25) % 8; int b = tid/200;
    float s = b1[o];
    const float* mrow = msum + (b*8+t)*64;
    for (int c=0;c<64;c++) s += (mrow[c]*INV_XY_) * w1[o*64+c];
    kern[(b*8+t)*25 + o] = s;
}

// ---------------- final dynamic depthwise 5x5 conv on h_in ----------------
__global__ __launch_bounds__(256) void k_final(const float* __restrict__ h,
        const float* __restrict__ kern, float* __restrict__ out){
    int gidx = blockIdx.x*256 + threadIdx.x;          // 4718592 threads, 4 y each
    int yq = gidx % 24; int r = gidx / 24;
    int x = r % 96; r /= 96;
    int t = r % 8;  r /= 8;
    int c = r % 64; int b = r / 64;
    int y0 = yq*4;
    const float* kp = kern + (b*8+t)*25;
    float kv[25];
    #pragma unroll
    for (int i=0;i<25;i++) kv[i] = kp[i];
    const float* hp = h + ((size_t)(b*64+c)*8 + t)*9216;
    float acc[4] = {0.f,0.f,0.f,0.f};
    #pragma unroll
    for (int dx=0; dx<5; dx++){
        int xxr = x + dx - 2;
        if (xxr < 0 || xxr >= 96) continue;
        const float* row = hp + xxr*96;
        float rv[8];
        #pragma unroll
        for (int m=0;m<8;m++){
            int yy = y0 - 2 + m;
            rv[m] = (yy >= 0 && yy < 96) ? row[yy] : 0.f;
        }
        #pragma unroll
        for (int dy=0;dy<5;dy++){
            float w = kv[dx*5+dy];
            #pragma unroll
            for (int j=0;j<4;j++) acc[j] += w * rv[j+dy];
        }
    }
    float* op = out + ((size_t)(b*64+c)*8 + t)*9216 + x*96 + y0;
    *(float4*)op = make_float4(acc[0],acc[1],acc[2],acc[3]);
}

// ---------------- launch ----------------
extern "C" void kernel_launch(void* const* d_in, const int* in_sizes, int n_in,
                              void* d_out, int out_size, void* d_ws, size_t ws_size,
                              hipStream_t stream){
    const float* h    = (const float*)d_in[0];
    const float* w0   = (const float*)d_in[1];
    const float* cb0  = (const float*)d_in[2];
    const float* bn0g = (const float*)d_in[3];
    const float* bn0b = (const float*)d_in[4];
    const float* bn1g = (const float*)d_in[5];
    const float* bn1b = (const float*)d_in[6];
    const float* wqkv = (const float*)d_in[7];
    const float* bqkv = (const float*)d_in[8];
    const float* wo   = (const float*)d_in[9];
    const float* bo   = (const float*)d_in[10];
    const float* w1   = (const float*)d_in[11];
    const float* b1   = (const float*)d_in[12];

    char* ws = (char*)d_ws;
    float* x0            = (float*)(ws + OFF_X0);
    __hip_bfloat16* x2   = (__hip_bfloat16*)(ws + OFF_X2);
    float* wT            = (float*)(ws + OFF_WT);
    float* sum0          = (float*)(ws + OFF_SUM0);
    float* sq0           = (float*)(ws + OFF_SQ0);
    float* sum1          = (float*)(ws + OFF_SUM1);
    float* sq1           = (float*)(ws + OFF_SQ1);
    float* msum          = (float*)(ws + OFF_M);
    float* sc0           = (float*)(ws + OFF_SC0);
    float* sh0           = (float*)(ws + OFF_SH0);
    float* sc1           = (float*)(ws + OFF_SC1);
    float* sh1           = (float*)(ws + OFF_SH1);
    float* kern          = (float*)(ws + OFF_KERN);
    float* outp          = (float*)d_out;

    hipMemsetAsync(ws + OFF_SUM0, 0, ZBYTES, stream);
    k_prep  <<<144, 256, 0, stream>>>(w0, wT);
    k_conv0 <<<dim3(144, 32), 256, 0, stream>>>(h, wT, cb0, x0, sum0, sq0);
    k_fin   <<<1, 64, 0, stream>>>(sum0, sq0, bn0g, bn0b, sc0, sh0, INV_BN_);
    k_attn  <<<dim3(6, 96, 4), 256, 0, stream>>>(x0, sc0, sh0, wqkv, bqkv, wo, bo, x2);
    k_stats1<<<576, 256, 0, stream>>>(x2, sum1, sq1);
    k_fin   <<<1, 64, 0, stream>>>(sum1, sq1, bn1g, bn1b, sc1, sh1, INV_BN_);
    k_m     <<<dim3(24, 4), 256, 0, stream>>>(x2, sc1, sh1, msum);
    k_kern  <<<4, 256, 0, stream>>>(msum, w1, b1, kern);
    k_final <<<18432, 256, 0, stream>>>(h, kern, outp);
}

// Round 2
// 781.073 us; speedup vs baseline: 1.4013x; 1.4013x over previous
//
#include <hip/hip_runtime.h>
#include <hip/hip_bf16.h>

typedef __attribute__((ext_vector_type(8))) short  short8;
typedef __attribute__((ext_vector_type(4))) short  short4v;
typedef __attribute__((ext_vector_type(4))) float  floatx4;
typedef unsigned short ushort_t;
typedef __attribute__((ext_vector_type(4))) unsigned short ushort4v;

// ---------------- problem dims ----------------
constexpr int B_=4, C_=64, T_=8, X_=96, Y_=96;
constexpr int XY_  = X_*Y_;            // 9216
constexpr int TOT_ = B_*C_*T_*XY_;     // 18874368
constexpr float EPS_   = 1e-5f;
constexpr float SLOPE_ = 0.01f;
constexpr float QSC_   = 0.35355339059327373f;   // 1/sqrt(8)
constexpr float INV_BN_ = 1.0f/294912.0f;        // 1/(B*T*X*Y)
constexpr float INV_XY_ = 1.0f/9216.0f;

// ---------------- ws layout (bytes) ----------------
constexpr size_t OFF_X0   = 0;                         // bf16 [n][t][c] token-major
constexpr size_t OFF_X2   = (size_t)TOT_*2;            // bf16 [n][t][c]
constexpr size_t OFF_WT   = OFF_X2 + (size_t)TOT_*2;   // f32 [ci][k][co] 36864
constexpr size_t OFF_QP   = OFF_WT + 147456;           // bf16 packed qkv B-frags 12288
constexpr size_t OFF_WP   = OFF_QP + 24576;            // bf16 packed wo  B-frags 4096
constexpr size_t OFF_SUM0 = OFF_WP + 8192;
constexpr size_t OFF_SQ0  = OFF_SUM0 + 256;
constexpr size_t OFF_SUM1 = OFF_SQ0 + 256;
constexpr size_t OFF_SQ1  = OFF_SUM1 + 256;
constexpr size_t OFF_M    = OFF_SQ1 + 256;             // 2048 f32 [b][t][c]
constexpr size_t ZBYTES   = 1024 + 8192;               // zero from OFF_SUM0
constexpr size_t OFF_SC0  = OFF_M + 8192;
constexpr size_t OFF_SH0  = OFF_SC0 + 256;
constexpr size_t OFF_SC1  = OFF_SH0 + 256;
constexpr size_t OFF_SH1  = OFF_SC1 + 256;
constexpr size_t OFF_KERN = OFF_SH1 + 256;             // 800 f32 [b][t][25]

__device__ __forceinline__ float leaky_(float v){ return v >= 0.f ? v : SLOPE_*v; }
__device__ __forceinline__ float bf2f(ushort_t u){
    union { unsigned int i; float f; } c; c.i = ((unsigned int)u) << 16; return c.f;
}
__device__ __forceinline__ ushort_t f2bf(float f){
    __hip_bfloat16 b = __float2bfloat16(f);
    return *reinterpret_cast<ushort_t*>(&b);
}

// ---------------- K0: weight transpose + MFMA B-fragment packing ----------------
__global__ void k_prep(const float* __restrict__ w0, const float* __restrict__ wqkv,
                       const float* __restrict__ wo,
                       float* __restrict__ wT, short* __restrict__ qP, short* __restrict__ wP){
    int i = blockIdx.x*256 + threadIdx.x;             // 53248 total
    if (i < 36864){
        int co = i & 63; int k = (i >> 6) % 9; int ci = i / 576;
        wT[i] = w0[co*576 + ci*9 + k];
    } else if (i < 49152){
        int pos = i - 36864;
        int j = pos & 7, lane = (pos>>3)&63, kb = (pos>>9)&1, nt = pos>>10;
        int n = nt*16 + (lane&15);
        int c = kb*32 + (lane>>4)*8 + j;
        qP[pos] = (short)f2bf(wqkv[n*64 + c]);
    } else if (i < 53248){
        int pos = i - 49152;
        int j = pos & 7, lane = (pos>>3)&63, kb = (pos>>9)&1, nt = pos>>10;
        int n = nt*16 + (lane&15);
        int c = kb*32 + (lane>>4)*8 + j;
        wP[pos] = (short)f2bf(wo[n*64 + c]);
    }
}

// ---------------- K1: conv0 (1x3x3, pad 1) + bias -> x0 bf16 token-major; BN0 stats ----
__global__ __launch_bounds__(256) void k_conv0(const float* __restrict__ h,
        const float* __restrict__ wT, const float* __restrict__ bias,
        ushort_t* __restrict__ x0, float* __restrict__ sum0, float* __restrict__ sq0){
    __shared__ float s_in[64*6*20];                   // [ci][row 6][col 20] (18 valid)
    int bt = blockIdx.y; int b = bt >> 3, t = bt & 7;
    int tile = blockIdx.x; int xt = tile / 6, yt = tile % 6;
    int xr0 = xt*4, y0 = yt*16;
    const float* hb = h + ((size_t)(b*64)*8 + t)*9216;
    for (int s = threadIdx.x; s < 7680; s += 256){
        int col = s % 20; int r = (s/20) % 6; int ci = s / 120;
        int xx = xr0 + r - 1, yy = y0 + col - 1;
        float v = 0.f;
        if (col < 18 && xx >= 0 && xx < 96 && yy >= 0 && yy < 96)
            v = hb[(size_t)ci*73728 + xx*96 + yy];
        s_in[s] = v;
    }
    __syncthreads();
    int co = threadIdx.x & 63, g = threadIdx.x >> 6;
    float bv = bias[co];
    float acc[16];
    #pragma unroll
    for (int j=0;j<16;j++) acc[j] = bv;
    for (int ci=0; ci<64; ci++){
        float w[9];
        #pragma unroll
        for (int k=0;k<9;k++) w[k] = wT[(ci*9+k)*64 + co];
        #pragma unroll
        for (int dx=0; dx<3; dx++){
            const float* row = &s_in[ci*120 + (g+dx)*20];
            float r[18];
            #pragma unroll
            for (int m=0;m<18;m++) r[m] = row[m];
            #pragma unroll
            for (int dy=0;dy<3;dy++){
                float wv = w[dx*3+dy];
                #pragma unroll
                for (int j=0;j<16;j++) acc[j] += wv * r[j+dy];
            }
        }
    }
    // write bf16 token-major: elem = ((n)*8 + t)*64 + co, n = b*9216+(xr0+g)*96+y0+j
    size_t base = ((size_t)(b*9216 + (xr0+g)*96 + y0)*8 + t)*64 + co;
    #pragma unroll
    for (int j=0;j<16;j++) x0[base + (size_t)j*512] = f2bf(acc[j]);
    // fused BN0 partial stats (exact f32 pre-rounding)
    float ls=0.f, lq=0.f;
    #pragma unroll
    for (int j=0;j<16;j++){ ls += acc[j]; lq += acc[j]*acc[j]; }
    __syncthreads();
    float* red = s_in;
    red[g*64+co] = ls; red[256 + g*64+co] = lq;
    __syncthreads();
    if (threadIdx.x < 64){
        int c = threadIdx.x;
        float a = red[c] + red[64+c] + red[128+c] + red[192+c];
        float q = red[256+c] + red[320+c] + red[384+c] + red[448+c];
        atomicAdd(&sum0[c], a);
        atomicAdd(&sq0[c], q);
    }
}

// ---------------- finalize BN scale/shift ----------------
__global__ void k_fin(const float* __restrict__ sum, const float* __restrict__ sq,
                      const float* __restrict__ g, const float* __restrict__ be,
                      float* __restrict__ scale, float* __restrict__ shift, float inv_n){
    int c = threadIdx.x;
    float mu = sum[c]*inv_n;
    float var = sq[c]*inv_n - mu*mu;
    float rs = rsqrtf(var + EPS_);
    float sc = g[c]*rs;
    scale[c] = sc; shift[c] = be[c] - mu*sc;
}

// ---------------- A12: BN0+leaky + MHA (MFMA qkv/out_proj) + residual -> x2 bf16 -------
// block 256 thr = 4 waves; 8 positions (b, xx, y0..y0+7) x 8 t = 64 tokens
__global__ __launch_bounds__(256) void k_attn(const ushort_t* __restrict__ x0,
        const float* __restrict__ sc0, const float* __restrict__ sh0,
        const short* __restrict__ qP, const float* __restrict__ bqkv,
        const short* __restrict__ wP, const float* __restrict__ bo,
        ushort_t* __restrict__ x2){
    __shared__ __align__(16) char smem[59392];
    ushort_t* x1s = (ushort_t*)smem;                 // [64][72] bf16  (phase 0..1)
    float*    qsF = (float*)(smem + 9216);           // [64][196] f32 swizzled (phase 1..2)
    ushort_t* om  = (ushort_t*)smem;                 // [64][72] bf16  (phase 2..3, reuse x1s)
    ushort_t* oo  = (ushort_t*)(smem + 9216);        // [64][72] bf16  (phase 3..4, reuse qsF)

    int tid = threadIdx.x;
    int b = blockIdx.z, xx = blockIdx.y, y0 = blockIdx.x*8;
    size_t slab = ((size_t)(b*9216 + xx*96 + y0)) * 512;   // ushort elements

    // ---- phase 0: load slab, BN0+leaky, stage bf16 [tok][c] ----
    #pragma unroll
    for (int it=0; it<4; ++it){
        int g = tid + it*256;                 // ushort4 group 0..1023
        int e0 = g*4, tok = g>>4, c0 = e0 & 63;
        ushort4v xv = *(const ushort4v*)(x0 + slab + e0);
        floatx4 sc = *(const floatx4*)(sc0 + c0);
        floatx4 sh = *(const floatx4*)(sh0 + c0);
        short4v st;
        #pragma unroll
        for (int j=0;j<4;++j)
            st[j] = (short)f2bf(leaky_(bf2f(xv[j])*sc[j] + sh[j]));
        *(short4v*)(x1s + tok*72 + c0) = st;
    }
    __syncthreads();

    int lane = tid & 63, w = tid >> 6;
    int c16 = lane & 15, qd = lane >> 4;

    // ---- phase 1: qkv GEMM [64x64]@[64x192] via MFMA; D -> swizzled qsF[tok][ch] ----
    {
        short8 a0 = *(const short8*)(x1s + (w*16 + c16)*72 + qd*8);
        short8 a1 = *(const short8*)(x1s + (w*16 + c16)*72 + 32 + qd*8);
        #pragma unroll
        for (int nt=0; nt<12; ++nt){
            float bv = bqkv[nt*16 + c16];
            floatx4 acc = {bv,bv,bv,bv};
            short8 b0 = *(const short8*)(qP + (nt*2+0)*512 + lane*8);
            short8 b1 = *(const short8*)(qP + (nt*2+1)*512 + lane*8);
            acc = __builtin_amdgcn_mfma_f32_16x16x32_bf16(a0, b0, acc, 0, 0, 0);
            acc = __builtin_amdgcn_mfma_f32_16x16x32_bf16(a1, b1, acc, 0, 0, 0);
            if (nt < 4){ acc[0]*=QSC_; acc[1]*=QSC_; acc[2]*=QSC_; acc[3]*=QSC_; }
            int n = nt*16 + c16, chunk = n>>2, sub = n&3;
            #pragma unroll
            for (int r=0;r<4;++r){
                int row = w*16 + qd*4 + r;
                int p = row >> 3;
                qsF[row*196 + ((chunk ^ p)<<2) + sub] = acc[r];
            }
        }
    }
    __syncthreads();

    // ---- phase 2: per-(tok,head) scores/softmax/PV; h is wave-uniform ----
    {
        int tok = lane + 0*(tid&0);           // tok = tid&63 == lane
        int p = tok >> 3;
        #pragma unroll
        for (int i=0;i<2;++i){
            int h = (tid>>6) + 4*i;
            floatx4 qa = *(const floatx4*)(qsF + tok*196 + ((( 2*h   ) ^ p)<<2));
            floatx4 qb = *(const floatx4*)(qsF + tok*196 + ((( 2*h+1 ) ^ p)<<2));
            float sv[8]; float mx = -1e30f;
            #pragma unroll
            for (int kt=0; kt<8; ++kt){
                int row = p*8 + kt;
                floatx4 ka = *(const floatx4*)(qsF + row*196 + (((16+2*h) ^ p)<<2));
                floatx4 kb = *(const floatx4*)(qsF + row*196 + (((17+2*h) ^ p)<<2));
                float s = qa[0]*ka[0]+qa[1]*ka[1]+qa[2]*ka[2]+qa[3]*ka[3]
                        + qb[0]*kb[0]+qb[1]*kb[1]+qb[2]*kb[2]+qb[3]*kb[3];
                sv[kt] = s; mx = fmaxf(mx, s);
            }
            float ssum = 0.f;
            #pragma unroll
            for (int kt=0;kt<8;++kt){ sv[kt] = __expf(sv[kt]-mx); ssum += sv[kt]; }
            float inv = 1.f/ssum;
            floatx4 o0 = {0,0,0,0}, o1 = {0,0,0,0};
            #pragma unroll
            for (int kt=0;kt<8;++kt){
                int row = p*8 + kt;
                floatx4 va = *(const floatx4*)(qsF + row*196 + (((32+2*h) ^ p)<<2));
                floatx4 vb = *(const floatx4*)(qsF + row*196 + (((33+2*h) ^ p)<<2));
                o0 += sv[kt]*va; o1 += sv[kt]*vb;
            }
            short8 ov;
            #pragma unroll
            for (int j=0;j<4;++j){ ov[j] = (short)f2bf(o0[j]*inv); ov[4+j] = (short)f2bf(o1[j]*inv); }
            *(short8*)(om + tok*72 + h*8) = ov;
        }
    }
    __syncthreads();

    // ---- phase 3: out_proj [64x64]@[64x64] via MFMA (+bo) -> oo[tok][c] ----
    {
        short8 A0 = *(const short8*)(om + (w*16 + c16)*72 + qd*8);
        short8 A1 = *(const short8*)(om + (w*16 + c16)*72 + 32 + qd*8);
        #pragma unroll
        for (int nt=0; nt<4; ++nt){
            float bv = bo[nt*16 + c16];
            floatx4 acc = {bv,bv,bv,bv};
            short8 b0 = *(const short8*)(wP + (nt*2+0)*512 + lane*8);
            short8 b1 = *(const short8*)(wP + (nt*2+1)*512 + lane*8);
            acc = __builtin_amdgcn_mfma_f32_16x16x32_bf16(A0, b0, acc, 0, 0, 0);
            acc = __builtin_amdgcn_mfma_f32_16x16x32_bf16(A1, b1, acc, 0, 0, 0);
            #pragma unroll
            for (int r=0;r<4;++r){
                int row = w*16 + qd*4 + r;
                oo[row*72 + nt*16 + c16] = f2bf(acc[r]);
            }
        }
    }
    __syncthreads();

    // ---- phase 4: residual x1 (recompute from x0) + oo -> x2 ----
    #pragma unroll
    for (int it=0; it<4; ++it){
        int g = tid + it*256;
        int e0 = g*4, tok = g>>4, c0 = e0 & 63;
        ushort4v xv = *(const ushort4v*)(x0 + slab + e0);
        floatx4 sc = *(const floatx4*)(sc0 + c0);
        floatx4 sh = *(const floatx4*)(sh0 + c0);
        short4v ov = *(const short4v*)(oo + tok*72 + c0);
        ushort4v st;
        #pragma unroll
        for (int j=0;j<4;++j){
            float x1v = leaky_(bf2f(xv[j])*sc[j] + sh[j]);
            st[j] = f2bf(x1v + bf2f((ushort_t)ov[j]));
        }
        *(ushort4v*)(x2 + slab + e0) = st;
    }
}

// ---------------- stats over x2 (BN1) ----------------
__global__ __launch_bounds__(256) void k_stats1(const ushort_t* __restrict__ x2,
        float* __restrict__ sum1, float* __restrict__ sq1){
    __shared__ float red[512];
    int c = threadIdx.x & 63, w = threadIdx.x >> 6;
    size_t tk0 = (size_t)blockIdx.x * 512;
    float s = 0.f, q = 0.f;
    for (int tk = w; tk < 512; tk += 4){
        float v = bf2f(x2[(tk0 + tk)*64 + c]);
        s += v; q += v*v;
    }
    red[w*64+c] = s; red[256 + w*64+c] = q;
    __syncthreads();
    if (threadIdx.x < 64){
        int cc = threadIdx.x;
        float a = red[cc] + red[64+cc] + red[128+cc] + red[192+cc];
        float qq = red[256+cc] + red[320+cc] + red[384+cc] + red[448+cc];
        atomicAdd(&sum1[cc], a);
        atomicAdd(&sq1[cc], qq);
    }
}

// ---------------- m partial sums: sum over (x,y) of leaky(bn1(x2)) ----------------
__global__ __launch_bounds__(256) void k_m(const ushort_t* __restrict__ x2,
        const float* __restrict__ sc1, const float* __restrict__ sh1,
        float* __restrict__ msum){
    int c = threadIdx.x & 63, tg = threadIdx.x >> 6;
    int b = blockIdx.y, chunk = blockIdx.x;
    float macc[8] = {0,0,0,0,0,0,0,0};
    float sc = sc1[c], sh = sh1[c];
    int xy_end = chunk*96 + 96;
    for (int xy = chunk*96 + tg; xy < xy_end; xy += 4){
        size_t base = ((size_t)(b*9216 + xy)*8)*64 + c;
        #pragma unroll
        for (int t=0;t<8;t++){
            float v = bf2f(x2[base + (size_t)t*64]);
            macc[t] += leaky_(v*sc + sh);
        }
    }
    #pragma unroll
    for (int t=0;t<8;t++) atomicAdd(&msum[(b*8+t)*64 + c], macc[t]);
}

// ---------------- kern[b][t][25] = conv1(m) ----------------
__global__ void k_kern(const float* __restrict__ msum, const float* __restrict__ w1,
                       const float* __restrict__ b1, float* __restrict__ kern){
    int tid = blockIdx.x*256 + threadIdx.x;
    if (tid >= 800) return;
    int o = tid % 25; int t = (tid/25) % 8; int b = tid/200;
    float s = b1[o];
    const float* mrow = msum + (b*8+t)*64;
    for (int c=0;c<64;c++) s += (mrow[c]*INV_XY_) * w1[o*64+c];
    kern[(b*8+t)*25 + o] = s;
}

// ---------------- final dynamic depthwise 5x5 conv on h_in ----------------
__global__ __launch_bounds__(256) void k_final(const float* __restrict__ h,
        const float* __restrict__ kern, float* __restrict__ out){
    int gidx = blockIdx.x*256 + threadIdx.x;
    int yq = gidx % 24; int r = gidx / 24;
    int x = r % 96; r /= 96;
    int t = r % 8;  r /= 8;
    int c = r % 64; int b = r / 64;
    int y0 = yq*4;
    const float* kp = kern + (b*8+t)*25;
    float kv[25];
    #pragma unroll
    for (int i=0;i<25;i++) kv[i] = kp[i];
    const float* hp = h + ((size_t)(b*64+c)*8 + t)*9216;
    float acc[4] = {0.f,0.f,0.f,0.f};
    #pragma unroll
    for (int dx=0; dx<5; dx++){
        int xxr = x + dx - 2;
        if (xxr < 0 || xxr >= 96) continue;
        const float* row = hp + xxr*96;
        float rv[8];
        #pragma unroll
        for (int m=0;m<8;m++){
            int yy = y0 - 2 + m;
            rv[m] = (yy >= 0 && yy < 96) ? row[yy] : 0.f;
        }
        #pragma unroll
        for (int dy=0;dy<5;dy++){
            float w = kv[dx*5+dy];
            #pragma unroll
            for (int j=0;j<4;j++) acc[j] += w * rv[j+dy];
        }
    }
    float* op = out + ((size_t)(b*64+c)*8 + t)*9216 + x*96 + y0;
    *(float4*)op = make_float4(acc[0],acc[1],acc[2],acc[3]);
}

// ---------------- launch ----------------
extern "C" void kernel_launch(void* const* d_in, const int* in_sizes, int n_in,
                              void* d_out, int out_size, void* d_ws, size_t ws_size,
                              hipStream_t stream){
    const float* h    = (const float*)d_in[0];
    const float* w0   = (const float*)d_in[1];
    const float* cb0  = (const float*)d_in[2];
    const float* bn0g = (const float*)d_in[3];
    const float* bn0b = (const float*)d_in[4];
    const float* bn1g = (const float*)d_in[5];
    const float* bn1b = (const float*)d_in[6];
    const float* wqkv = (const float*)d_in[7];
    const float* bqkv = (const float*)d_in[8];
    const float* wo   = (const float*)d_in[9];
    const float* bo   = (const float*)d_in[10];
    const float* w1   = (const float*)d_in[11];
    const float* b1   = (const float*)d_in[12];

    char* ws = (char*)d_ws;
    ushort_t* x0  = (ushort_t*)(ws + OFF_X0);
    ushort_t* x2  = (ushort_t*)(ws + OFF_X2);
    float* wT     = (float*)(ws + OFF_WT);
    short* qP     = (short*)(ws + OFF_QP);
    short* wP     = (short*)(ws + OFF_WP);
    float* sum0   = (float*)(ws + OFF_SUM0);
    float* sq0    = (float*)(ws + OFF_SQ0);
    float* sum1   = (float*)(ws + OFF_SUM1);
    float* sq1    = (float*)(ws + OFF_SQ1);
    float* msum   = (float*)(ws + OFF_M);
    float* sc0    = (float*)(ws + OFF_SC0);
    float* sh0    = (float*)(ws + OFF_SH0);
    float* sc1    = (float*)(ws + OFF_SC1);
    float* sh1    = (float*)(ws + OFF_SH1);
    float* kern   = (float*)(ws + OFF_KERN);
    float* outp   = (float*)d_out;

    hipMemsetAsync(ws + OFF_SUM0, 0, ZBYTES, stream);
    k_prep  <<<208, 256, 0, stream>>>(w0, wqkv, wo, wT, qP, wP);
    k_conv0 <<<dim3(144, 32), 256, 0, stream>>>(h, wT, cb0, x0, sum0, sq0);
    k_fin   <<<1, 64, 0, stream>>>(sum0, sq0, bn0g, bn0b, sc0, sh0, INV_BN_);
    k_attn  <<<dim3(12, 96, 4), 256, 0, stream>>>(x0, sc0, sh0, qP, bqkv, wP, bo, x2);
    k_stats1<<<576, 256, 0, stream>>>(x2, sum1, sq1);
    k_fin   <<<1, 64, 0, stream>>>(sum1, sq1, bn1g, bn1b, sc1, sh1, INV_BN_);
    k_m     <<<dim3(96, 4), 256, 0, stream>>>(x2, sc1, sh1, msum);
    k_kern  <<<4, 256, 0, stream>>>(msum, w1, b1, kern);
    k_final <<<18432, 256, 0, stream>>>(h, kern, outp);
}

// Round 3
// 528.213 us; speedup vs baseline: 2.0722x; 1.4787x over previous
//
#include <hip/hip_runtime.h>
#include <hip/hip_bf16.h>

typedef __attribute__((ext_vector_type(8))) short  short8;
typedef __attribute__((ext_vector_type(4))) short  short4v;
typedef __attribute__((ext_vector_type(4))) float  floatx4;
typedef unsigned short ushort_t;
typedef __attribute__((ext_vector_type(4))) unsigned short ushort4v;
typedef __attribute__((ext_vector_type(8))) unsigned short ushort8v;

// ---------------- problem dims ----------------
constexpr int B_=4, C_=64, T_=8, X_=96, Y_=96;
constexpr int XY_  = X_*Y_;            // 9216
constexpr int TOT_ = B_*C_*T_*XY_;     // 18874368
constexpr float EPS_   = 1e-5f;
constexpr float SLOPE_ = 0.01f;
constexpr float QSC_   = 0.35355339059327373f;   // 1/sqrt(8)
constexpr float INV_BN_ = 1.0f/294912.0f;        // 1/(B*T*X*Y)
constexpr float INV_XY_ = 1.0f/9216.0f;

// ---------------- ws layout (bytes) ----------------
constexpr size_t OFF_HT   = 0;                         // bf16 [bt][x][y][ci] 37748736
constexpr size_t OFF_X0   = 37748736;                  // bf16 [n][t][c] token-major
constexpr size_t OFF_X2   = OFF_X0 + (size_t)TOT_*2;   // bf16 [n][t][c]
constexpr size_t OFF_WB   = OFF_X2 + (size_t)TOT_*2;   // bf16 conv0 B-frags 36864
constexpr size_t OFF_QP   = OFF_WB + 73728;            // bf16 packed qkv B-frags 12288
constexpr size_t OFF_WP   = OFF_QP + 24576;            // bf16 packed wo  B-frags 4096
constexpr size_t OFF_SUM0 = OFF_WP + 8192;
constexpr size_t OFF_SQ0  = OFF_SUM0 + 256;
constexpr size_t OFF_SUM1 = OFF_SQ0 + 256;
constexpr size_t OFF_SQ1  = OFF_SUM1 + 256;
constexpr size_t OFF_M    = OFF_SQ1 + 256;             // 2048 f32 [b][t][c]
constexpr size_t ZBYTES   = 1024 + 8192;               // zero from OFF_SUM0
constexpr size_t OFF_SC0  = OFF_M + 8192;
constexpr size_t OFF_SH0  = OFF_SC0 + 256;
constexpr size_t OFF_SC1  = OFF_SH0 + 256;
constexpr size_t OFF_SH1  = OFF_SC1 + 256;
constexpr size_t OFF_KERN = OFF_SH1 + 256;             // 800 f32 [b][t][25]

__device__ __forceinline__ float leaky_(float v){ return v >= 0.f ? v : SLOPE_*v; }
__device__ __forceinline__ float bf2f(ushort_t u){
    union { unsigned int i; float f; } c; c.i = ((unsigned int)u) << 16; return c.f;
}
__device__ __forceinline__ ushort_t f2bf(float f){
    __hip_bfloat16 b = __float2bfloat16(f);
    return *reinterpret_cast<ushort_t*>(&b);
}

// ---------------- K0: MFMA B-fragment packing for conv0 / qkv / out_proj --------------
__global__ void k_prep(const float* __restrict__ w0, const float* __restrict__ wqkv,
                       const float* __restrict__ wo,
                       ushort_t* __restrict__ wB, short* __restrict__ qP, short* __restrict__ wP){
    int i = blockIdx.x*256 + threadIdx.x;             // 53248 total
    if (i < 36864){
        // wB[frag][lane][j]; frag = (tap*2+kb)*4+nt ; B[k=ci][n=co]
        int j = i & 7, lane = (i>>3) & 63, frag = i >> 9;
        int nt = frag & 3, kb = (frag>>2) & 1, tap = frag >> 3;
        int co = nt*16 + (lane & 15);
        int ci = kb*32 + (lane>>4)*8 + j;
        wB[i] = f2bf(w0[co*576 + ci*9 + tap]);
    } else if (i < 49152){
        int pos = i - 36864;
        int j = pos & 7, lane = (pos>>3)&63, kb = (pos>>9)&1, nt = pos>>10;
        int n = nt*16 + (lane&15);
        int c = kb*32 + (lane>>4)*8 + j;
        qP[pos] = (short)f2bf(wqkv[n*64 + c]);
    } else if (i < 53248){
        int pos = i - 49152;
        int j = pos & 7, lane = (pos>>3)&63, kb = (pos>>9)&1, nt = pos>>10;
        int n = nt*16 + (lane&15);
        int c = kb*32 + (lane>>4)*8 + j;
        wP[pos] = (short)f2bf(wo[n*64 + c]);
    }
}

// ---------------- K0b: transpose h -> hT bf16 token-major [bt][x][y][ci] --------------
__global__ __launch_bounds__(256) void k_hT(const float* __restrict__ h,
                                            ushort_t* __restrict__ hT){
    __shared__ float s[96*65];
    int x = blockIdx.x, bt = blockIdx.y;
    int b = bt >> 3, t = bt & 7;
    int c = threadIdx.x >> 2, yq = threadIdx.x & 3;
    const float* hp = h + ((size_t)(b*64 + c)*8 + t)*9216 + x*96 + yq*24;
    #pragma unroll
    for (int i=0;i<6;i++){
        float4 v = *(const float4*)(hp + i*4);
        int y = yq*24 + i*4;
        s[(y+0)*65 + c] = v.x;
        s[(y+1)*65 + c] = v.y;
        s[(y+2)*65 + c] = v.z;
        s[(y+3)*65 + c] = v.w;
    }
    __syncthreads();
    ushort_t* op = hT + ((size_t)(bt*96 + x)*96)*64;
    int o0 = threadIdx.x*24;
    #pragma unroll
    for (int v8=0; v8<3; ++v8){
        ushort8v pk;
        #pragma unroll
        for (int j=0;j<8;j++){
            int o = o0 + v8*8 + j;
            pk[j] = f2bf(s[(o>>6)*65 + (o&63)]);
        }
        *(ushort8v*)(op + o0 + v8*8) = pk;
    }
}

// ---------------- K1: conv0 via tap-decomposed implicit MFMA GEMM; BN0 stats ----------
// block 256 thr = 4 waves; wave = one x-row (96 y) x all 64 co; block = 4 x-rows, one bt
__global__ __launch_bounds__(256) void k_conv0(const ushort_t* __restrict__ hT,
        const ushort_t* __restrict__ wB, const float* __restrict__ bias,
        ushort_t* __restrict__ x0, float* __restrict__ sum0, float* __restrict__ sq0){
    __shared__ float red[512];
    int tid = threadIdx.x;
    int lane = tid & 63, w = tid >> 6;
    int m = lane & 15, q = lane >> 4;
    int bt = blockIdx.y, b = bt >> 3, t = bt & 7;
    int xr = blockIdx.x*4 + w;
    floatx4 acc[6][4];
    #pragma unroll
    for (int nt=0; nt<4; ++nt){
        float bv = bias[nt*16 + m];
        #pragma unroll
        for (int mt=0; mt<6; ++mt) acc[mt][nt] = {bv,bv,bv,bv};
    }
    const ushort_t* hbase = hT + (size_t)bt*589824;     // 9216*64
    #pragma unroll
    for (int tap=0; tap<9; ++tap){
        int dx = tap/3, dy = tap%3;
        int xx = xr + dx - 1;
        if ((unsigned)xx >= 96u) continue;              // wave-uniform (zero pad in x)
        const ushort_t* hrow = hbase + (size_t)xx*6144 + q*8;
        #pragma unroll
        for (int kb=0; kb<2; ++kb){
            short8 bf[4];
            #pragma unroll
            for (int nt=0; nt<4; ++nt)
                bf[nt] = *(const short8*)(wB + ((tap*2+kb)*4 + nt)*512 + lane*8);
            #pragma unroll
            for (int mt=0; mt<6; ++mt){
                int y = mt*16 + m + dy - 1;
                short8 a = {0,0,0,0,0,0,0,0};
                if ((unsigned)y < 96u)                  // per-lane y pad mask
                    a = *(const short8*)(hrow + y*64 + kb*32);
                #pragma unroll
                for (int nt=0; nt<4; ++nt)
                    acc[mt][nt] = __builtin_amdgcn_mfma_f32_16x16x32_bf16(a, bf[nt], acc[mt][nt], 0,0,0);
            }
        }
    }
    // store x0 (token-major bf16) + fused BN0 stats on exact f32 acc
    float ls[4] = {0,0,0,0}, lq[4] = {0,0,0,0};
    size_t outb = ((size_t)(b*9216 + xr*96)*8 + t)*64;
    #pragma unroll
    for (int mt=0; mt<6; ++mt){
        #pragma unroll
        for (int nt=0; nt<4; ++nt){
            #pragma unroll
            for (int r=0; r<4; ++r){
                float v = acc[mt][nt][r];
                ls[nt] += v; lq[nt] += v*v;
                int y = mt*16 + q*4 + r;
                x0[outb + (size_t)y*512 + nt*16 + m] = f2bf(v);
            }
        }
    }
    #pragma unroll
    for (int nt=0; nt<4; ++nt){
        ls[nt] += __shfl_xor(ls[nt], 16); ls[nt] += __shfl_xor(ls[nt], 32);
        lq[nt] += __shfl_xor(lq[nt], 16); lq[nt] += __shfl_xor(lq[nt], 32);
    }
    if (lane < 16){
        #pragma unroll
        for (int nt=0; nt<4; ++nt){
            red[w*64 + nt*16 + lane]       = ls[nt];
            red[256 + w*64 + nt*16 + lane] = lq[nt];
        }
    }
    __syncthreads();
    if (tid < 64){
        float a  = red[tid] + red[64+tid] + red[128+tid] + red[192+tid];
        float qq = red[256+tid] + red[320+tid] + red[384+tid] + red[448+tid];
        atomicAdd(&sum0[tid], a);
        atomicAdd(&sq0[tid], qq);
    }
}

// ---------------- finalize BN scale/shift ----------------
__global__ void k_fin(const float* __restrict__ sum, const float* __restrict__ sq,
                      const float* __restrict__ g, const float* __restrict__ be,
                      float* __restrict__ scale, float* __restrict__ shift, float inv_n){
    int c = threadIdx.x;
    float mu = sum[c]*inv_n;
    float var = sq[c]*inv_n - mu*mu;
    float rs = rsqrtf(var + EPS_);
    float sc = g[c]*rs;
    scale[c] = sc; shift[c] = be[c] - mu*sc;
}

// ---------------- A12: BN0+leaky + MHA (MFMA qkv/out_proj) + residual -> x2 bf16 -------
__global__ __launch_bounds__(256) void k_attn(const ushort_t* __restrict__ x0,
        const float* __restrict__ sc0, const float* __restrict__ sh0,
        const short* __restrict__ qP, const float* __restrict__ bqkv,
        const short* __restrict__ wP, const float* __restrict__ bo,
        ushort_t* __restrict__ x2){
    __shared__ __align__(16) char smem[59392];
    ushort_t* x1s = (ushort_t*)smem;                 // [64][72] bf16  (phase 0..1)
    float*    qsF = (float*)(smem + 9216);           // [64][196] f32 swizzled (phase 1..2)
    ushort_t* om  = (ushort_t*)smem;                 // [64][72] bf16  (phase 2..3, reuse x1s)
    ushort_t* oo  = (ushort_t*)(smem + 9216);        // [64][72] bf16  (phase 3..4, reuse qsF)

    int tid = threadIdx.x;
    int b = blockIdx.z, xx = blockIdx.y, y0 = blockIdx.x*8;
    size_t slab = ((size_t)(b*9216 + xx*96 + y0)) * 512;   // ushort elements

    #pragma unroll
    for (int it=0; it<4; ++it){
        int g = tid + it*256;
        int e0 = g*4, tok = g>>4, c0 = e0 & 63;
        ushort4v xv = *(const ushort4v*)(x0 + slab + e0);
        floatx4 sc = *(const floatx4*)(sc0 + c0);
        floatx4 sh = *(const floatx4*)(sh0 + c0);
        short4v st;
        #pragma unroll
        for (int j=0;j<4;++j)
            st[j] = (short)f2bf(leaky_(bf2f(xv[j])*sc[j] + sh[j]));
        *(short4v*)(x1s + tok*72 + c0) = st;
    }
    __syncthreads();

    int lane = tid & 63, w = tid >> 6;
    int c16 = lane & 15, qd = lane >> 4;

    // ---- phase 1: qkv GEMM via MFMA; D -> swizzled qsF[tok][ch] ----
    {
        short8 a0 = *(const short8*)(x1s + (w*16 + c16)*72 + qd*8);
        short8 a1 = *(const short8*)(x1s + (w*16 + c16)*72 + 32 + qd*8);
        #pragma unroll
        for (int nt=0; nt<12; ++nt){
            float bv = bqkv[nt*16 + c16];
            floatx4 acc = {bv,bv,bv,bv};
            short8 b0 = *(const short8*)(qP + (nt*2+0)*512 + lane*8);
            short8 b1 = *(const short8*)(qP + (nt*2+1)*512 + lane*8);
            acc = __builtin_amdgcn_mfma_f32_16x16x32_bf16(a0, b0, acc, 0, 0, 0);
            acc = __builtin_amdgcn_mfma_f32_16x16x32_bf16(a1, b1, acc, 0, 0, 0);
            if (nt < 4){ acc[0]*=QSC_; acc[1]*=QSC_; acc[2]*=QSC_; acc[3]*=QSC_; }
            int n = nt*16 + c16, chunk = n>>2, sub = n&3;
            #pragma unroll
            for (int r=0;r<4;++r){
                int row = w*16 + qd*4 + r;
                int p = row >> 3;
                qsF[row*196 + ((chunk ^ p)<<2) + sub] = acc[r];
            }
        }
    }
    __syncthreads();

    // ---- phase 2: per-(tok,head) scores/softmax/PV ----
    {
        int tok = lane;
        int p = tok >> 3;
        #pragma unroll
        for (int i=0;i<2;++i){
            int h = (tid>>6) + 4*i;
            floatx4 qa = *(const floatx4*)(qsF + tok*196 + ((( 2*h   ) ^ p)<<2));
            floatx4 qb = *(const floatx4*)(qsF + tok*196 + ((( 2*h+1 ) ^ p)<<2));
            float sv[8]; float mx = -1e30f;
            #pragma unroll
            for (int kt=0; kt<8; ++kt){
                int row = p*8 + kt;
                floatx4 ka = *(const floatx4*)(qsF + row*196 + (((16+2*h) ^ p)<<2));
                floatx4 kb = *(const floatx4*)(qsF + row*196 + (((17+2*h) ^ p)<<2));
                float s = qa[0]*ka[0]+qa[1]*ka[1]+qa[2]*ka[2]+qa[3]*ka[3]
                        + qb[0]*kb[0]+qb[1]*kb[1]+qb[2]*kb[2]+qb[3]*kb[3];
                sv[kt] = s; mx = fmaxf(mx, s);
            }
            float ssum = 0.f;
            #pragma unroll
            for (int kt=0;kt<8;++kt){ sv[kt] = __expf(sv[kt]-mx); ssum += sv[kt]; }
            float inv = 1.f/ssum;
            floatx4 o0 = {0,0,0,0}, o1 = {0,0,0,0};
            #pragma unroll
            for (int kt=0;kt<8;++kt){
                int row = p*8 + kt;
                floatx4 va = *(const floatx4*)(qsF + row*196 + (((32+2*h) ^ p)<<2));
                floatx4 vb = *(const floatx4*)(qsF + row*196 + (((33+2*h) ^ p)<<2));
                o0 += sv[kt]*va; o1 += sv[kt]*vb;
            }
            short8 ov;
            #pragma unroll
            for (int j=0;j<4;++j){ ov[j] = (short)f2bf(o0[j]*inv); ov[4+j] = (short)f2bf(o1[j]*inv); }
            *(short8*)(om + tok*72 + h*8) = ov;
        }
    }
    __syncthreads();

    // ---- phase 3: out_proj via MFMA (+bo) -> oo[tok][c] ----
    {
        short8 A0 = *(const short8*)(om + (w*16 + c16)*72 + qd*8);
        short8 A1 = *(const short8*)(om + (w*16 + c16)*72 + 32 + qd*8);
        #pragma unroll
        for (int nt=0; nt<4; ++nt){
            float bv = bo[nt*16 + c16];
            floatx4 acc = {bv,bv,bv,bv};
            short8 b0 = *(const short8*)(wP + (nt*2+0)*512 + lane*8);
            short8 b1 = *(const short8*)(wP + (nt*2+1)*512 + lane*8);
            acc = __builtin_amdgcn_mfma_f32_16x16x32_bf16(A0, b0, acc, 0, 0, 0);
            acc = __builtin_amdgcn_mfma_f32_16x16x32_bf16(A1, b1, acc, 0, 0, 0);
            #pragma unroll
            for (int r=0;r<4;++r){
                int row = w*16 + qd*4 + r;
                oo[row*72 + nt*16 + c16] = f2bf(acc[r]);
            }
        }
    }
    __syncthreads();

    // ---- phase 4: residual x1 (recompute from x0) + oo -> x2 ----
    #pragma unroll
    for (int it=0; it<4; ++it){
        int g = tid + it*256;
        int e0 = g*4, tok = g>>4, c0 = e0 & 63;
        ushort4v xv = *(const ushort4v*)(x0 + slab + e0);
        floatx4 sc = *(const floatx4*)(sc0 + c0);
        floatx4 sh = *(const floatx4*)(sh0 + c0);
        short4v ov = *(const short4v*)(oo + tok*72 + c0);
        ushort4v st;
        #pragma unroll
        for (int j=0;j<4;++j){
            float x1v = leaky_(bf2f(xv[j])*sc[j] + sh[j]);
            st[j] = f2bf(x1v + bf2f((ushort_t)ov[j]));
        }
        *(ushort4v*)(x2 + slab + e0) = st;
    }
}

// ---------------- stats over x2 (BN1) ----------------
__global__ __launch_bounds__(256) void k_stats1(const ushort_t* __restrict__ x2,
        float* __restrict__ sum1, float* __restrict__ sq1){
    __shared__ float red[512];
    int c = threadIdx.x & 63, w = threadIdx.x >> 6;
    size_t tk0 = (size_t)blockIdx.x * 512;
    float s = 0.f, q = 0.f;
    for (int tk = w; tk < 512; tk += 4){
        float v = bf2f(x2[(tk0 + tk)*64 + c]);
        s += v; q += v*v;
    }
    red[w*64+c] = s; red[256 + w*64+c] = q;
    __syncthreads();
    if (threadIdx.x < 64){
        int cc = threadIdx.x;
        float a = red[cc] + red[64+cc] + red[128+cc] + red[192+cc];
        float qq = red[256+cc] + red[320+cc] + red[384+cc] + red[448+cc];
        atomicAdd(&sum1[cc], a);
        atomicAdd(&sq1[cc], qq);
    }
}

// ---------------- m partial sums: sum over (x,y) of leaky(bn1(x2)) ----------------
__global__ __launch_bounds__(256) void k_m(const ushort_t* __restrict__ x2,
        const float* __restrict__ sc1, const float* __restrict__ sh1,
        float* __restrict__ msum){
    int c = threadIdx.x & 63, tg = threadIdx.x >> 6;
    int b = blockIdx.y, chunk = blockIdx.x;
    float macc[8] = {0,0,0,0,0,0,0,0};
    float sc = sc1[c], sh = sh1[c];
    int xy_end = chunk*96 + 96;
    for (int xy = chunk*96 + tg; xy < xy_end; xy += 4){
        size_t base = ((size_t)(b*9216 + xy)*8)*64 + c;
        #pragma unroll
        for (int t=0;t<8;t++){
            float v = bf2f(x2[base + (size_t)t*64]);
            macc[t] += leaky_(v*sc + sh);
        }
    }
    #pragma unroll
    for (int t=0;t<8;t++) atomicAdd(&msum[(b*8+t)*64 + c], macc[t]);
}

// ---------------- kern[b][t][25] = conv1(m) ----------------
__global__ void k_kern(const float* __restrict__ msum, const float* __restrict__ w1,
                       const float* __restrict__ b1, float* __restrict__ kern){
    int tid = blockIdx.x*256 + threadIdx.x;
    if (tid >= 800) return;
    int o = tid % 25; int t = (tid/25) % 8; int b = tid/200;
    float s = b1[o];
    const float* mrow = msum + (b*8+t)*64;
    for (int c=0;c<64;c++) s += (mrow[c]*INV_XY_) * w1[o*64+c];
    kern[(b*8+t)*25 + o] = s;
}

// ---------------- final dynamic depthwise 5x5 conv on h_in ----------------
__global__ __launch_bounds__(256) void k_final(const float* __restrict__ h,
        const float* __restrict__ kern, float* __restrict__ out){
    int gidx = blockIdx.x*256 + threadIdx.x;
    int yq = gidx % 24; int r = gidx / 24;
    int x = r % 96; r /= 96;
    int t = r % 8;  r /= 8;
    int c = r % 64; int b = r / 64;
    int y0 = yq*4;
    const float* kp = kern + (b*8+t)*25;
    float kv[25];
    #pragma unroll
    for (int i=0;i<25;i++) kv[i] = kp[i];
    const float* hp = h + ((size_t)(b*64+c)*8 + t)*9216;
    float acc[4] = {0.f,0.f,0.f,0.f};
    #pragma unroll
    for (int dx=0; dx<5; dx++){
        int xxr = x + dx - 2;
        if (xxr < 0 || xxr >= 96) continue;
        const float* row = hp + xxr*96;
        float rv[8];
        #pragma unroll
        for (int m=0;m<8;m++){
            int yy = y0 - 2 + m;
            rv[m] = (yy >= 0 && yy < 96) ? row[yy] : 0.f;
        }
        #pragma unroll
        for (int dy=0;dy<5;dy++){
            float w = kv[dx*5+dy];
            #pragma unroll
            for (int j=0;j<4;j++) acc[j] += w * rv[j+dy];
        }
    }
    float* op = out + ((size_t)(b*64+c)*8 + t)*9216 + x*96 + y0;
    *(float4*)op = make_float4(acc[0],acc[1],acc[2],acc[3]);
}

// ---------------- launch ----------------
extern "C" void kernel_launch(void* const* d_in, const int* in_sizes, int n_in,
                              void* d_out, int out_size, void* d_ws, size_t ws_size,
                              hipStream_t stream){
    const float* h    = (const float*)d_in[0];
    const float* w0   = (const float*)d_in[1];
    const float* cb0  = (const float*)d_in[2];
    const float* bn0g = (const float*)d_in[3];
    const float* bn0b = (const float*)d_in[4];
    const float* bn1g = (const float*)d_in[5];
    const float* bn1b = (const float*)d_in[6];
    const float* wqkv = (const float*)d_in[7];
    const float* bqkv = (const float*)d_in[8];
    const float* wo   = (const float*)d_in[9];
    const float* bo   = (const float*)d_in[10];
    const float* w1   = (const float*)d_in[11];
    const float* b1   = (const float*)d_in[12];

    char* ws = (char*)d_ws;
    ushort_t* hT  = (ushort_t*)(ws + OFF_HT);
    ushort_t* x0  = (ushort_t*)(ws + OFF_X0);
    ushort_t* x2  = (ushort_t*)(ws + OFF_X2);
    ushort_t* wB  = (ushort_t*)(ws + OFF_WB);
    short* qP     = (short*)(ws + OFF_QP);
    short* wP     = (short*)(ws + OFF_WP);
    float* sum0   = (float*)(ws + OFF_SUM0);
    float* sq0    = (float*)(ws + OFF_SQ0);
    float* sum1   = (float*)(ws + OFF_SUM1);
    float* sq1    = (float*)(ws + OFF_SQ1);
    float* msum   = (float*)(ws + OFF_M);
    float* sc0    = (float*)(ws + OFF_SC0);
    float* sh0    = (float*)(ws + OFF_SH0);
    float* sc1    = (float*)(ws + OFF_SC1);
    float* sh1    = (float*)(ws + OFF_SH1);
    float* kern   = (float*)(ws + OFF_KERN);
    float* outp   = (float*)d_out;

    hipMemsetAsync(ws + OFF_SUM0, 0, ZBYTES, stream);
    k_prep  <<<208, 256, 0, stream>>>(w0, wqkv, wo, wB, qP, wP);
    k_hT    <<<dim3(96, 32), 256, 0, stream>>>(h, hT);
    k_conv0 <<<dim3(24, 32), 256, 0, stream>>>(hT, wB, cb0, x0, sum0, sq0);
    k_fin   <<<1, 64, 0, stream>>>(sum0, sq0, bn0g, bn0b, sc0, sh0, INV_BN_);
    k_attn  <<<dim3(12, 96, 4), 256, 0, stream>>>(x0, sc0, sh0, qP, bqkv, wP, bo, x2);
    k_stats1<<<576, 256, 0, stream>>>(x2, sum1, sq1);
    k_fin   <<<1, 64, 0, stream>>>(sum1, sq1, bn1g, bn1b, sc1, sh1, INV_BN_);
    k_m     <<<dim3(96, 4), 256, 0, stream>>>(x2, sc1, sh1, msum);
    k_kern  <<<4, 256, 0, stream>>>(msum, w1, b1, kern);
    k_final <<<18432, 256, 0, stream>>>(h, kern, outp);
}

// Round 4
// 416.675 us; speedup vs baseline: 2.6268x; 1.2677x over previous
//
#include <hip/hip_runtime.h>
#include <hip/hip_bf16.h>

typedef __attribute__((ext_vector_type(8))) short  short8;
typedef __attribute__((ext_vector_type(4))) short  short4v;
typedef __attribute__((ext_vector_type(4))) float  floatx4;
typedef unsigned short ushort_t;
typedef __attribute__((ext_vector_type(4))) unsigned short ushort4v;
typedef __attribute__((ext_vector_type(8))) unsigned short ushort8v;

// ---------------- problem dims ----------------
constexpr int B_=4, C_=64, T_=8, X_=96, Y_=96;
constexpr int XY_  = X_*Y_;            // 9216
constexpr int TOT_ = B_*C_*T_*XY_;     // 18874368
constexpr float EPS_   = 1e-5f;
constexpr float SLOPE_ = 0.01f;
constexpr float QSC_   = 0.35355339059327373f;   // 1/sqrt(8)
constexpr float INV_BN_ = 1.0f/294912.0f;        // 1/(B*T*X*Y)
constexpr float INV_XY_ = 1.0f/9216.0f;

// ---------------- ws layout (bytes) ----------------
constexpr size_t OFF_HT   = 0;                         // bf16 [bt][x][y][ci] 37748736
constexpr size_t OFF_X0   = 37748736;                  // bf16 [n][t][c] token-major
constexpr size_t OFF_X2   = OFF_X0 + (size_t)TOT_*2;   // bf16 [n][t][c]
constexpr size_t OFF_WB   = OFF_X2 + (size_t)TOT_*2;   // bf16 conv0 B-frags 36864
constexpr size_t OFF_QP   = OFF_WB + 73728;            // bf16 packed qkv B-frags 12288
constexpr size_t OFF_WP   = OFF_QP + 24576;            // bf16 packed wo  B-frags 4096
constexpr size_t OFF_SUM0 = OFF_WP + 8192;
constexpr size_t OFF_SQ0  = OFF_SUM0 + 256;
constexpr size_t OFF_SUM1 = OFF_SQ0 + 256;
constexpr size_t OFF_SQ1  = OFF_SUM1 + 256;
constexpr size_t OFF_M    = OFF_SQ1 + 256;             // 2048 f32 [b][t][c]
constexpr size_t ZBYTES   = 1024 + 8192;               // zero from OFF_SUM0
constexpr size_t OFF_SC0  = OFF_M + 8192;
constexpr size_t OFF_SH0  = OFF_SC0 + 256;
constexpr size_t OFF_SC1  = OFF_SH0 + 256;
constexpr size_t OFF_SH1  = OFF_SC1 + 256;
constexpr size_t OFF_KERN = OFF_SH1 + 256;             // 800 f32 [b][t][25]

__device__ __forceinline__ float leaky_(float v){ return v >= 0.f ? v : SLOPE_*v; }
__device__ __forceinline__ float bf2f(ushort_t u){
    union { unsigned int i; float f; } c; c.i = ((unsigned int)u) << 16; return c.f;
}
__device__ __forceinline__ ushort_t f2bf(float f){
    __hip_bfloat16 b = __float2bfloat16(f);
    return *reinterpret_cast<ushort_t*>(&b);
}

// ---------------- K0: MFMA B-fragment packing for conv0 / qkv / out_proj --------------
__global__ void k_prep(const float* __restrict__ w0, const float* __restrict__ wqkv,
                       const float* __restrict__ wo,
                       ushort_t* __restrict__ wB, short* __restrict__ qP, short* __restrict__ wP){
    int i = blockIdx.x*256 + threadIdx.x;             // 53248 total
    if (i < 36864){
        int j = i & 7, lane = (i>>3) & 63, frag = i >> 9;
        int nt = frag & 3, kb = (frag>>2) & 1, tap = frag >> 3;
        int co = nt*16 + (lane & 15);
        int ci = kb*32 + (lane>>4)*8 + j;
        wB[i] = f2bf(w0[co*576 + ci*9 + tap]);
    } else if (i < 49152){
        int pos = i - 36864;
        int j = pos & 7, lane = (pos>>3)&63, kb = (pos>>9)&1, nt = pos>>10;
        int n = nt*16 + (lane&15);
        int c = kb*32 + (lane>>4)*8 + j;
        qP[pos] = (short)f2bf(wqkv[n*64 + c]);
    } else if (i < 53248){
        int pos = i - 49152;
        int j = pos & 7, lane = (pos>>3)&63, kb = (pos>>9)&1, nt = pos>>10;
        int n = nt*16 + (lane&15);
        int c = kb*32 + (lane>>4)*8 + j;
        wP[pos] = (short)f2bf(wo[n*64 + c]);
    }
}

// ---------------- K0b: transpose h -> hT bf16 token-major [bt][x][y][ci] --------------
__global__ __launch_bounds__(256) void k_hT(const float* __restrict__ h,
                                            ushort_t* __restrict__ hT){
    __shared__ float s[96*65];
    int x = blockIdx.x, bt = blockIdx.y;
    int b = bt >> 3, t = bt & 7;
    int c = threadIdx.x >> 2, yq = threadIdx.x & 3;
    const float* hp = h + ((size_t)(b*64 + c)*8 + t)*9216 + x*96 + yq*24;
    #pragma unroll
    for (int i=0;i<6;i++){
        float4 v = *(const float4*)(hp + i*4);
        int y = yq*24 + i*4;
        s[(y+0)*65 + c] = v.x;
        s[(y+1)*65 + c] = v.y;
        s[(y+2)*65 + c] = v.z;
        s[(y+3)*65 + c] = v.w;
    }
    __syncthreads();
    ushort_t* op = hT + ((size_t)(bt*96 + x)*96)*64;
    int o0 = threadIdx.x*24;
    #pragma unroll
    for (int v8=0; v8<3; ++v8){
        ushort8v pk;
        #pragma unroll
        for (int j=0;j<8;j++){
            int o = o0 + v8*8 + j;
            pk[j] = f2bf(s[(o>>6)*65 + (o&63)]);
        }
        *(ushort8v*)(op + o0 + v8*8) = pk;
    }
}

// ---------------- K1: conv0 via tap-decomposed implicit MFMA GEMM; BN0 stats ----------
__global__ __launch_bounds__(256) void k_conv0(const ushort_t* __restrict__ hT,
        const ushort_t* __restrict__ wB, const float* __restrict__ bias,
        ushort_t* __restrict__ x0, float* __restrict__ sum0, float* __restrict__ sq0){
    __shared__ float red[512];
    int tid = threadIdx.x;
    int lane = tid & 63, w = tid >> 6;
    int m = lane & 15, q = lane >> 4;
    int bt = blockIdx.y, b = bt >> 3, t = bt & 7;
    int xr = blockIdx.x*4 + w;
    floatx4 acc[6][4];
    #pragma unroll
    for (int nt=0; nt<4; ++nt){
        float bv = bias[nt*16 + m];
        #pragma unroll
        for (int mt=0; mt<6; ++mt) acc[mt][nt] = {bv,bv,bv,bv};
    }
    const ushort_t* hbase = hT + (size_t)bt*589824;
    #pragma unroll
    for (int tap=0; tap<9; ++tap){
        int dx = tap/3, dy = tap%3;
        int xx = xr + dx - 1;
        if ((unsigned)xx >= 96u) continue;
        const ushort_t* hrow = hbase + (size_t)xx*6144 + q*8;
        #pragma unroll
        for (int kb=0; kb<2; ++kb){
            short8 bf[4];
            #pragma unroll
            for (int nt=0; nt<4; ++nt)
                bf[nt] = *(const short8*)(wB + ((tap*2+kb)*4 + nt)*512 + lane*8);
            #pragma unroll
            for (int mt=0; mt<6; ++mt){
                int y = mt*16 + m + dy - 1;
                short8 a = {0,0,0,0,0,0,0,0};
                if ((unsigned)y < 96u)
                    a = *(const short8*)(hrow + y*64 + kb*32);
                #pragma unroll
                for (int nt=0; nt<4; ++nt)
                    acc[mt][nt] = __builtin_amdgcn_mfma_f32_16x16x32_bf16(a, bf[nt], acc[mt][nt], 0,0,0);
            }
        }
    }
    float ls[4] = {0,0,0,0}, lq[4] = {0,0,0,0};
    size_t outb = ((size_t)(b*9216 + xr*96)*8 + t)*64;
    #pragma unroll
    for (int mt=0; mt<6; ++mt){
        #pragma unroll
        for (int nt=0; nt<4; ++nt){
            #pragma unroll
            for (int r=0; r<4; ++r){
                float v = acc[mt][nt][r];
                ls[nt] += v; lq[nt] += v*v;
                int y = mt*16 + q*4 + r;
                x0[outb + (size_t)y*512 + nt*16 + m] = f2bf(v);
            }
        }
    }
    #pragma unroll
    for (int nt=0; nt<4; ++nt){
        ls[nt] += __shfl_xor(ls[nt], 16); ls[nt] += __shfl_xor(ls[nt], 32);
        lq[nt] += __shfl_xor(lq[nt], 16); lq[nt] += __shfl_xor(lq[nt], 32);
    }
    if (lane < 16){
        #pragma unroll
        for (int nt=0; nt<4; ++nt){
            red[w*64 + nt*16 + lane]       = ls[nt];
            red[256 + w*64 + nt*16 + lane] = lq[nt];
        }
    }
    __syncthreads();
    if (tid < 64){
        float a  = red[tid] + red[64+tid] + red[128+tid] + red[192+tid];
        float qq = red[256+tid] + red[320+tid] + red[384+tid] + red[448+tid];
        atomicAdd(&sum0[tid], a);
        atomicAdd(&sq0[tid], qq);
    }
}

// ---------------- finalize BN scale/shift ----------------
__global__ void k_fin(const float* __restrict__ sum, const float* __restrict__ sq,
                      const float* __restrict__ g, const float* __restrict__ be,
                      float* __restrict__ scale, float* __restrict__ shift, float inv_n){
    int c = threadIdx.x;
    float mu = sum[c]*inv_n;
    float var = sq[c]*inv_n - mu*mu;
    float rs = rsqrtf(var + EPS_);
    float sc = g[c]*rs;
    scale[c] = sc; shift[c] = be[c] - mu*sc;
}

// ---------------- A12: BN0+leaky + MHA + residual -> x2 bf16 ; fused BN1 stats --------
__global__ __launch_bounds__(256) void k_attn(const ushort_t* __restrict__ x0,
        const float* __restrict__ sc0, const float* __restrict__ sh0,
        const short* __restrict__ qP, const float* __restrict__ bqkv,
        const short* __restrict__ wP, const float* __restrict__ bo,
        ushort_t* __restrict__ x2, float* __restrict__ sum1, float* __restrict__ sq1){
    __shared__ __align__(16) char smem[59392];
    ushort_t* x1s = (ushort_t*)smem;                 // [64][72] bf16  (phase 0..1)
    float*    qsF = (float*)(smem + 9216);           // [64][196] f32 swizzled (phase 1..2)
    ushort_t* om  = (ushort_t*)smem;                 // [64][72] bf16  (phase 2..3, reuse x1s)
    ushort_t* oo  = (ushort_t*)(smem + 9216);        // [64][72] bf16  (phase 3..4, reuse qsF)

    int tid = threadIdx.x;
    int b = blockIdx.z, xx = blockIdx.y, y0 = blockIdx.x*8;
    size_t slab = ((size_t)(b*9216 + xx*96 + y0)) * 512;

    #pragma unroll
    for (int it=0; it<4; ++it){
        int g = tid + it*256;
        int e0 = g*4, tok = g>>4, c0 = e0 & 63;
        ushort4v xv = *(const ushort4v*)(x0 + slab + e0);
        floatx4 sc = *(const floatx4*)(sc0 + c0);
        floatx4 sh = *(const floatx4*)(sh0 + c0);
        short4v st;
        #pragma unroll
        for (int j=0;j<4;++j)
            st[j] = (short)f2bf(leaky_(bf2f(xv[j])*sc[j] + sh[j]));
        *(short4v*)(x1s + tok*72 + c0) = st;
    }
    __syncthreads();

    int lane = tid & 63, w = tid >> 6;
    int c16 = lane & 15, qd = lane >> 4;

    // ---- phase 1: qkv GEMM via MFMA; D -> swizzled qsF[tok][ch] ----
    {
        short8 a0 = *(const short8*)(x1s + (w*16 + c16)*72 + qd*8);
        short8 a1 = *(const short8*)(x1s + (w*16 + c16)*72 + 32 + qd*8);
        #pragma unroll
        for (int nt=0; nt<12; ++nt){
            float bv = bqkv[nt*16 + c16];
            floatx4 acc = {bv,bv,bv,bv};
            short8 b0 = *(const short8*)(qP + (nt*2+0)*512 + lane*8);
            short8 b1 = *(const short8*)(qP + (nt*2+1)*512 + lane*8);
            acc = __builtin_amdgcn_mfma_f32_16x16x32_bf16(a0, b0, acc, 0, 0, 0);
            acc = __builtin_amdgcn_mfma_f32_16x16x32_bf16(a1, b1, acc, 0, 0, 0);
            if (nt < 4){ acc[0]*=QSC_; acc[1]*=QSC_; acc[2]*=QSC_; acc[3]*=QSC_; }
            int n = nt*16 + c16, chunk = n>>2, sub = n&3;
            #pragma unroll
            for (int r=0;r<4;++r){
                int row = w*16 + qd*4 + r;
                int p = row >> 3;
                qsF[row*196 + ((chunk ^ p)<<2) + sub] = acc[r];
            }
        }
    }
    __syncthreads();

    // ---- phase 2: per-(tok,head) scores/softmax/PV ----
    {
        int tok = lane;
        int p = tok >> 3;
        #pragma unroll
        for (int i=0;i<2;++i){
            int h = (tid>>6) + 4*i;
            floatx4 qa = *(const floatx4*)(qsF + tok*196 + ((( 2*h   ) ^ p)<<2));
            floatx4 qb = *(const floatx4*)(qsF + tok*196 + ((( 2*h+1 ) ^ p)<<2));
            float sv[8]; float mx = -1e30f;
            #pragma unroll
            for (int kt=0; kt<8; ++kt){
                int row = p*8 + kt;
                floatx4 ka = *(const floatx4*)(qsF + row*196 + (((16+2*h) ^ p)<<2));
                floatx4 kb = *(const floatx4*)(qsF + row*196 + (((17+2*h) ^ p)<<2));
                float s = qa[0]*ka[0]+qa[1]*ka[1]+qa[2]*ka[2]+qa[3]*ka[3]
                        + qb[0]*kb[0]+qb[1]*kb[1]+qb[2]*kb[2]+qb[3]*kb[3];
                sv[kt] = s; mx = fmaxf(mx, s);
            }
            float ssum = 0.f;
            #pragma unroll
            for (int kt=0;kt<8;++kt){ sv[kt] = __expf(sv[kt]-mx); ssum += sv[kt]; }
            float inv = 1.f/ssum;
            floatx4 o0 = {0,0,0,0}, o1 = {0,0,0,0};
            #pragma unroll
            for (int kt=0;kt<8;++kt){
                int row = p*8 + kt;
                floatx4 va = *(const floatx4*)(qsF + row*196 + (((32+2*h) ^ p)<<2));
                floatx4 vb = *(const floatx4*)(qsF + row*196 + (((33+2*h) ^ p)<<2));
                o0 += sv[kt]*va; o1 += sv[kt]*vb;
            }
            short8 ov;
            #pragma unroll
            for (int j=0;j<4;++j){ ov[j] = (short)f2bf(o0[j]*inv); ov[4+j] = (short)f2bf(o1[j]*inv); }
            *(short8*)(om + tok*72 + h*8) = ov;
        }
    }
    __syncthreads();

    // ---- phase 3: out_proj via MFMA (+bo) -> oo[tok][c] ----
    {
        short8 A0 = *(const short8*)(om + (w*16 + c16)*72 + qd*8);
        short8 A1 = *(const short8*)(om + (w*16 + c16)*72 + 32 + qd*8);
        #pragma unroll
        for (int nt=0; nt<4; ++nt){
            float bv = bo[nt*16 + c16];
            floatx4 acc = {bv,bv,bv,bv};
            short8 b0 = *(const short8*)(wP + (nt*2+0)*512 + lane*8);
            short8 b1 = *(const short8*)(wP + (nt*2+1)*512 + lane*8);
            acc = __builtin_amdgcn_mfma_f32_16x16x32_bf16(A0, b0, acc, 0, 0, 0);
            acc = __builtin_amdgcn_mfma_f32_16x16x32_bf16(A1, b1, acc, 0, 0, 0);
            #pragma unroll
            for (int r=0;r<4;++r){
                int row = w*16 + qd*4 + r;
                oo[row*72 + nt*16 + c16] = f2bf(acc[r]);
            }
        }
    }
    __syncthreads();

    // ---- phase 4: residual + store x2 ; accumulate BN1 partial stats ----
    float ls[4] = {0,0,0,0}, lq[4] = {0,0,0,0};
    #pragma unroll
    for (int it=0; it<4; ++it){
        int g = tid + it*256;
        int e0 = g*4, tok = g>>4, c0 = e0 & 63;
        ushort4v xv = *(const ushort4v*)(x0 + slab + e0);
        floatx4 sc = *(const floatx4*)(sc0 + c0);
        floatx4 sh = *(const floatx4*)(sh0 + c0);
        short4v ov = *(const short4v*)(oo + tok*72 + c0);
        ushort4v st;
        #pragma unroll
        for (int j=0;j<4;++j){
            float x1v = leaky_(bf2f(xv[j])*sc[j] + sh[j]);
            st[j] = f2bf(x1v + bf2f((ushort_t)ov[j]));
            float vr = bf2f(st[j]);
            ls[j] += vr; lq[j] += vr*vr;
        }
        *(ushort4v*)(x2 + slab + e0) = st;
    }
    __syncthreads();
    float* red = (float*)smem;                  // 2048 floats, fits in x1s region
    int slot = tid >> 4, c0s = (tid*4) & 63;    // c0 constant across its for each thread
    #pragma unroll
    for (int j=0;j<4;++j){
        red[slot*64 + c0s + j]        = ls[j];
        red[1024 + slot*64 + c0s + j] = lq[j];
    }
    __syncthreads();
    if (tid < 128){
        int c = tid & 63;
        const float* base = red + (tid>>6)*1024 + c;
        float a = 0.f;
        #pragma unroll
        for (int s=0;s<16;++s) a += base[s*64];
        atomicAdd((tid < 64) ? &sum1[c] : &sq1[c], a);
    }
}

// ---------------- m partial sums: sum over (x,y) of leaky(bn1(x2)) ----------------
__global__ __launch_bounds__(256) void k_m(const ushort_t* __restrict__ x2,
        const float* __restrict__ sc1, const float* __restrict__ sh1,
        float* __restrict__ msum){
    int c = threadIdx.x & 63, tg = threadIdx.x >> 6;
    int b = blockIdx.y, chunk = blockIdx.x;
    float macc[8] = {0,0,0,0,0,0,0,0};
    float sc = sc1[c], sh = sh1[c];
    int xy_end = chunk*96 + 96;
    for (int xy = chunk*96 + tg; xy < xy_end; xy += 4){
        size_t base = ((size_t)(b*9216 + xy)*8)*64 + c;
        #pragma unroll
        for (int t=0;t<8;t++){
            float v = bf2f(x2[base + (size_t)t*64]);
            macc[t] += leaky_(v*sc + sh);
        }
    }
    #pragma unroll
    for (int t=0;t<8;t++) atomicAdd(&msum[(b*8+t)*64 + c], macc[t]);
}

// ---------------- kern[b][t][25] = conv1(m) ----------------
__global__ void k_kern(const float* __restrict__ msum, const float* __restrict__ w1,
                       const float* __restrict__ b1, float* __restrict__ kern){
    int tid = blockIdx.x*256 + threadIdx.x;
    if (tid >= 800) return;
    int o = tid % 25; int t = (tid/25) % 8; int b = tid/200;
    float s = b1[o];
    const float* mrow = msum + (b*8+t)*64;
    for (int c=0;c<64;c++) s += (mrow[c]*INV_XY_) * w1[o*64+c];
    kern[(b*8+t)*25 + o] = s;
}

// ---------------- final dynamic depthwise 5x5 conv: LDS-tiled, 1 block per (b,c,t) ----
__global__ __launch_bounds__(256) void k_final(const float* __restrict__ h,
        const float* __restrict__ kern, float* __restrict__ out){
    __shared__ float s[100*104];                     // rows x+2 (0..99), cols y+4 (stride 104)
    int bct = blockIdx.x;                            // = ((b*64+c)*8+t)
    int b = bct >> 9, t = bct & 7;
    int tid = threadIdx.x;
    const float* hp = h + (size_t)bct*9216;
    // zero border strips only (rows 0,1,98,99 full; cols 0-3 & 100-103 for rows 2..97)
    for (int i = tid; i < 1184; i += 256){
        int row, col;
        if (i < 416){ int r4 = i/104; row = (r4<2) ? r4 : 96 + r4; col = i - r4*104; }
        else { int j = i - 416; row = 2 + (j>>3); int k = j & 7; col = (k<4) ? k : 96 + k; }
        s[row*104 + col] = 0.f;
    }
    // interior fill: 2304 coalesced float4 loads -> aligned b128 LDS writes
    for (int i = tid; i < 2304; i += 256){
        int e = i*4; int xx = e/96, yy = e%96;       // yy%4==0
        float4 v = *(const float4*)(hp + e);
        *(float4*)(&s[(xx+2)*104 + yy + 4]) = v;
    }
    const float* kp = kern + ((size_t)(b*8+t))*25;
    float kv[25];
    #pragma unroll
    for (int i=0;i<25;i++) kv[i] = kp[i];
    __syncthreads();
    int tx = tid & 15, ty = tid >> 4;
    int x0 = ty*6, y0 = tx*6;
    float acc[6][6];
    #pragma unroll
    for (int i=0;i<6;i++)
        #pragma unroll
        for (int j=0;j<6;j++) acc[i][j] = 0.f;
    #pragma unroll
    for (int r=0; r<10; ++r){
        float row[10];
        const float* sp = &s[(x0+r)*104 + y0 + 2];   // LDS col of h[.][y0-2] is y0+2
        #pragma unroll
        for (int c=0;c<10;c++) row[c] = sp[c];
        #pragma unroll
        for (int orow=0; orow<6; ++orow){
            if (orow > r || orow < r-4) continue;    // static after unroll
            int dx = r - orow;
            #pragma unroll
            for (int dy=0; dy<5; ++dy){
                float wv = kv[dx*5+dy];
                #pragma unroll
                for (int oc=0; oc<6; ++oc)
                    acc[orow][oc] += wv * row[oc+dy];
            }
        }
    }
    float* op = out + (size_t)bct*9216 + x0*96 + y0;
    #pragma unroll
    for (int orow=0; orow<6; ++orow)
        #pragma unroll
        for (int oc=0; oc<6; ++oc)
            op[orow*96 + oc] = acc[orow][oc];
}

// ---------------- launch ----------------
extern "C" void kernel_launch(void* const* d_in, const int* in_sizes, int n_in,
                              void* d_out, int out_size, void* d_ws, size_t ws_size,
                              hipStream_t stream){
    const float* h    = (const float*)d_in[0];
    const float* w0   = (const float*)d_in[1];
    const float* cb0  = (const float*)d_in[2];
    const float* bn0g = (const float*)d_in[3];
    const float* bn0b = (const float*)d_in[4];
    const float* bn1g = (const float*)d_in[5];
    const float* bn1b = (const float*)d_in[6];
    const float* wqkv = (const float*)d_in[7];
    const float* bqkv = (const float*)d_in[8];
    const float* wo   = (const float*)d_in[9];
    const float* bo   = (const float*)d_in[10];
    const float* w1   = (const float*)d_in[11];
    const float* b1   = (const float*)d_in[12];

    char* ws = (char*)d_ws;
    ushort_t* hT  = (ushort_t*)(ws + OFF_HT);
    ushort_t* x0  = (ushort_t*)(ws + OFF_X0);
    ushort_t* x2  = (ushort_t*)(ws + OFF_X2);
    ushort_t* wB  = (ushort_t*)(ws + OFF_WB);
    short* qP     = (short*)(ws + OFF_QP);
    short* wP     = (short*)(ws + OFF_WP);
    float* sum0   = (float*)(ws + OFF_SUM0);
    float* sq0    = (float*)(ws + OFF_SQ0);
    float* sum1   = (float*)(ws + OFF_SUM1);
    float* sq1    = (float*)(ws + OFF_SQ1);
    float* msum   = (float*)(ws + OFF_M);
    float* sc0    = (float*)(ws + OFF_SC0);
    float* sh0    = (float*)(ws + OFF_SH0);
    float* sc1    = (float*)(ws + OFF_SC1);
    float* sh1    = (float*)(ws + OFF_SH1);
    float* kern   = (float*)(ws + OFF_KERN);
    float* outp   = (float*)d_out;

    hipMemsetAsync(ws + OFF_SUM0, 0, ZBYTES, stream);
    k_prep  <<<208, 256, 0, stream>>>(w0, wqkv, wo, wB, qP, wP);
    k_hT    <<<dim3(96, 32), 256, 0, stream>>>(h, hT);
    k_conv0 <<<dim3(24, 32), 256, 0, stream>>>(hT, wB, cb0, x0, sum0, sq0);
    k_fin   <<<1, 64, 0, stream>>>(sum0, sq0, bn0g, bn0b, sc0, sh0, INV_BN_);
    k_attn  <<<dim3(12, 96, 4), 256, 0, stream>>>(x0, sc0, sh0, qP, bqkv, wP, bo, x2, sum1, sq1);
    k_fin   <<<1, 64, 0, stream>>>(sum1, sq1, bn1g, bn1b, sc1, sh1, INV_BN_);
    k_m     <<<dim3(96, 4), 256, 0, stream>>>(x2, sc1, sh1, msum);
    k_kern  <<<4, 256, 0, stream>>>(msum, w1, b1, kern);
    k_final <<<2048, 256, 0, stream>>>(h, kern, outp);
}